// Round 2
// baseline (82527.124 us; speedup 1.0000x reference)
//
#include <hip/hip_runtime.h>
#include <hip/hip_bf16.h>

// ---------------------------------------------------------------------------
// RSSMCore persistent-scan version.
//  - Pre: mask prep, xa_base = a@aw+zb (batched), x2_base = e@pe_w+ph_b (batched)
//  - One persistent kernel (512 blocks x 256 thr, 2 blocks/CU guaranteed by
//    __launch_bounds__(256,2)) runs all 64 steps with manual grid barriers.
//    gh(t+1) GEMM is pipelined into idle blocks of step t's x2/pp phases.
//  - Post: batched prior head (reuses proven round-1 tiled GEMM).
// All fp32 (no fp32 MFMA on CDNA4; bf16 would flip categorical argmax).
// ---------------------------------------------------------------------------

#define BK 32
#define LDP 68
#define NBLK 512

enum { TR_NONE = 0, TR_SCALEROW = 1, TR_LNELU = 2 };

struct GemmArgs {
  const float* A; int lda; const float* B; int ldb; int K; int ksplit;
  const float* A2; int lda2; const float* B2; int ldb2; int K2;
  int N; const float* bias;
  const float* t1s; const float* t1g; const float* t1b;
  float* C; int ldc; long partStride;
};

// XLA f32 tanh rational approximation (mul/add, no contraction) ------------
__device__ inline float xla_tanh(float x) {
  float ax = fabsf(x);
  float xc = fminf(fmaxf(x, -7.90531110763549805f), 7.90531110763549805f);
  float x2 = __fmul_rn(xc, xc);
  float p = -2.76076847742355e-16f;
  p = __fadd_rn(__fmul_rn(p, x2), 2.00018790482477e-13f);
  p = __fadd_rn(__fmul_rn(p, x2), -8.60467152213735e-11f);
  p = __fadd_rn(__fmul_rn(p, x2), 5.12229709037114e-08f);
  p = __fadd_rn(__fmul_rn(p, x2), 1.48572235717979e-05f);
  p = __fadd_rn(__fmul_rn(p, x2), 6.37261928875436e-04f);
  p = __fadd_rn(__fmul_rn(p, x2), 4.89352455891786e-03f);
  float num = __fmul_rn(xc, p);
  float q = 1.19825839466702e-06f;
  q = __fadd_rn(__fmul_rn(q, x2), 1.18534705686654e-04f);
  q = __fadd_rn(__fmul_rn(q, x2), 2.26843463243900e-03f);
  q = __fadd_rn(__fmul_rn(q, x2), 4.89352518554385e-03f);
  float r = __fdiv_rn(num, q);
  return ax < 0.0004f ? x : r;
}

__device__ inline float sigm(float x) { return 1.0f / (1.0f + expf(-x)); }

// Threefry2x32 (20 rounds), matches jax/_src/prng.py ------------------------
__device__ inline void tfround(unsigned& x0, unsigned& x1, int r) {
  x0 += x1; x1 = (x1 << r) | (x1 >> (32 - r)); x1 ^= x0;
}
__device__ inline uint2 threefry(unsigned k0, unsigned k1, unsigned c0, unsigned c1) {
  unsigned ks2 = k0 ^ k1 ^ 0x1BD11BDAu;
  unsigned x0 = c0 + k0, x1 = c1 + k1;
  tfround(x0, x1, 13); tfround(x0, x1, 15); tfround(x0, x1, 26); tfround(x0, x1, 6);
  x0 += k1; x1 += ks2 + 1u;
  tfround(x0, x1, 17); tfround(x0, x1, 29); tfround(x0, x1, 16); tfround(x0, x1, 24);
  x0 += ks2; x1 += k0 + 2u;
  tfround(x0, x1, 13); tfround(x0, x1, 15); tfround(x0, x1, 26); tfround(x0, x1, 6);
  x0 += k0; x1 += k1 + 3u;
  tfround(x0, x1, 17); tfround(x0, x1, 29); tfround(x0, x1, 16); tfround(x0, x1, 24);
  x0 += k1; x1 += ks2 + 4u;
  tfround(x0, x1, 13); tfround(x0, x1, 15); tfround(x0, x1, 26); tfround(x0, x1, 6);
  x0 += ks2; x1 += k0 + 5u;
  return make_uint2(x0, x1);
}

// ======================= round-1 proven tiled GEMM (pre/post) ==============
template <int TRA>
__device__ void gemm_tiles(float acc[4][4], float (*As)[LDP], float (*Bs)[LDP],
                           const float* A, int lda, const float* B, int ldb,
                           int kB, int kE, int mBase, int cBase, int N,
                           const float* s0, const float* g0, const float* b0) {
  const int tid = threadIdx.x;
  const int ar = tid >> 2;
  const int ak = (tid & 3) << 3;
  const int bk = tid >> 3;
  const int bc = (tid & 7) << 3;
  const int r0 = (tid >> 4) << 2;
  const int c0 = (tid & 15) << 2;

  float rowS = 1.f, rowM = 0.f, rowR = 1.f;
  if (TRA == TR_SCALEROW) rowS = s0[mBase + ar];
  else if (TRA == TR_LNELU) {
    rowM = s0[(mBase + ar) * 2];
    rowR = s0[(mBase + ar) * 2 + 1];
  }

  for (int kb = kB; kb < kE; kb += BK) {
    {
      const float* Ap = A + (long)(mBase + ar) * lda + kb + ak;
      float v[8];
      if (kb + ak + 7 < kE) {
        float4 u0 = *(const float4*)(Ap);
        float4 u1 = *(const float4*)(Ap + 4);
        v[0] = u0.x; v[1] = u0.y; v[2] = u0.z; v[3] = u0.w;
        v[4] = u1.x; v[5] = u1.y; v[6] = u1.z; v[7] = u1.w;
      } else {
#pragma unroll
        for (int i = 0; i < 8; i++) v[i] = (kb + ak + i < kE) ? Ap[i] : 0.f;
      }
#pragma unroll
      for (int i = 0; i < 8; i++) {
        int k = kb + ak + i;
        float x = 0.f;
        if (k < kE) {
          x = v[i];
          if (TRA == TR_SCALEROW) {
            x *= rowS;
          } else if (TRA == TR_LNELU) {
            x = (x - rowM) * rowR * g0[k] + b0[k];
            x = x > 0.f ? x : expm1f(x);
          }
        }
        As[ak + i][ar] = x;
      }
    }
    {
      int k = kb + bk;
      const float* Bp = B + (long)k * ldb + cBase + bc;
      if (k < kE && cBase + bc + 7 < N) {
        float4 u0 = *(const float4*)(Bp);
        float4 u1 = *(const float4*)(Bp + 4);
        Bs[bk][bc + 0] = u0.x; Bs[bk][bc + 1] = u0.y;
        Bs[bk][bc + 2] = u0.z; Bs[bk][bc + 3] = u0.w;
        Bs[bk][bc + 4] = u1.x; Bs[bk][bc + 5] = u1.y;
        Bs[bk][bc + 6] = u1.z; Bs[bk][bc + 7] = u1.w;
      } else {
#pragma unroll
        for (int i = 0; i < 8; i++)
          Bs[bk][bc + i] = (k < kE && cBase + bc + i < N) ? Bp[i] : 0.f;
      }
    }
    __syncthreads();
#pragma unroll
    for (int kk = 0; kk < BK; kk++) {
      float4 a4 = *(const float4*)&As[kk][r0];
      float4 b4 = *(const float4*)&Bs[kk][c0];
      float av[4] = {a4.x, a4.y, a4.z, a4.w};
      float bv[4] = {b4.x, b4.y, b4.z, b4.w};
#pragma unroll
      for (int i = 0; i < 4; i++)
#pragma unroll
        for (int j = 0; j < 4; j++) acc[i][j] += av[i] * bv[j];
    }
    __syncthreads();
  }
}

template <int TRA, int TRA2>
__global__ __launch_bounds__(256) void k_gemm(GemmArgs g) {
  __shared__ float As[BK][LDP];
  __shared__ float Bs[BK][LDP];
  const int nT = blockIdx.x, ks = blockIdx.y, mT = blockIdx.z;
  const int mBase = mT * 64, cBase = nT * 64;
  float acc[4][4] = {};
  int chunk = (((g.K + g.ksplit - 1) / g.ksplit) + 31) & ~31;
  int kB = ks * chunk, kE = min(g.K, kB + chunk);
  if (kB < kE)
    gemm_tiles<TRA>(acc, As, Bs, g.A, g.lda, g.B, g.ldb, kB, kE, mBase, cBase,
                    g.N, g.t1s, g.t1g, g.t1b);
  if (g.A2) {
    int chunk2 = (((g.K2 + g.ksplit - 1) / g.ksplit) + 31) & ~31;
    int kB2 = ks * chunk2, kE2 = min(g.K2, kB2 + chunk2);
    if (kB2 < kE2)
      gemm_tiles<TRA2>(acc, As, Bs, g.A2, g.lda2, g.B2, g.ldb2, kB2, kE2, mBase,
                       cBase, g.N, nullptr, nullptr, nullptr);
  }
  const int tid = threadIdx.x;
  const int r0 = (tid >> 4) << 2, c0 = (tid & 15) << 2;
  float* Cb = g.C + (long)ks * g.partStride;
#pragma unroll
  for (int i = 0; i < 4; i++) {
    float4 v = make_float4(acc[i][0], acc[i][1], acc[i][2], acc[i][3]);
    if (ks == 0 && g.bias) {
      int c = cBase + c0;
      v.x += (c + 0 < g.N) ? g.bias[c + 0] : 0.f;
      v.y += (c + 1 < g.N) ? g.bias[c + 1] : 0.f;
      v.z += (c + 2 < g.N) ? g.bias[c + 2] : 0.f;
      v.w += (c + 3 < g.N) ? g.bias[c + 3] : 0.f;
    }
    *(float4*)&Cb[(long)(mBase + r0 + i) * g.ldc + cBase + c0] = v;
  }
}

__global__ __launch_bounds__(256) void k_prstat(const float* xp, float* stats, int N) {
  int wave = threadIdx.x >> 6, lane = threadIdx.x & 63;
  int r = blockIdx.x * 4 + wave;
  float s = 0.f, sq = 0.f;
  for (int c = lane; c < N; c += 64) {
    float v = xp[(long)r * 1024 + c];
    s += v; sq += v * v;
  }
#pragma unroll
  for (int off = 32; off >= 1; off >>= 1) {
    s += __shfl_down(s, off);
    sq += __shfl_down(sq, off);
  }
  if (lane == 0) {
    float mean = s / N, var = sq / N - mean * mean;
    stats[r * 2] = mean;
    stats[r * 2 + 1] = 1.0f / sqrtf(var + 1e-3f);
  }
}

// ======================= persistent scan kernel ============================
struct ScanArgs {
  const float* z0; const float* h0;
  const float* zw; const float* gwi; const float* gwh;
  const float* gbi; const float* gbh;
  const float* ph_w; const float* pp_w; const float* pp_b;
  const float* in_g; const float* in_b; const float* po_g; const float* po_b;
  const float* mask;
  const float* xa_base; const float* x2_base;
  float* xa_parts; float* gi_parts; float* gh_parts;
  float* x2_parts; float* pp_parts; float* xe; float* x2e;
  float* posts; float* samples; float* feats; float* hlast; float* zlast;
  unsigned* bar;  // [0]=cnt (monotonic), [1]=gen
};

__device__ inline void gridbar(unsigned* bar, unsigned& lgen) {
  __threadfence();
  __syncthreads();
  lgen++;
  if (threadIdx.x == 0) {
    unsigned prev = __hip_atomic_fetch_add(&bar[0], 1u, __ATOMIC_ACQ_REL,
                                           __HIP_MEMORY_SCOPE_AGENT);
    if (prev == (unsigned)NBLK * lgen - 1u) {
      __hip_atomic_store(&bar[1], lgen, __ATOMIC_RELEASE, __HIP_MEMORY_SCOPE_AGENT);
    } else {
      while (__hip_atomic_load(&bar[1], __ATOMIC_ACQUIRE,
                               __HIP_MEMORY_SCOPE_AGENT) < lgen) {
        __builtin_amdgcn_s_sleep(8);
      }
    }
  }
  __syncthreads();
  __threadfence();
}

// 64-row x 64-col tile GEMM for one K-chunk (M fixed = 64, mBase = 0).
template <int TRA>
__device__ void phase_gemm(float (*As)[LDP], float (*Bs)[LDP],
                           const float* A, int lda, const float* B, int ldb,
                           int kB, int kE, int cBase, int N,
                           const float* rowScale,
                           float* C, int ldc,
                           const float* baseAdd,      // add [r*1024+c] if non-null (c<N)
                           const float* colBias) {    // add [c] if non-null (c<N)
  const int tid = threadIdx.x;
  const int ar = tid >> 2, ak = (tid & 3) << 3;
  const int bk = tid >> 3, bc = (tid & 7) << 3;
  const int r0 = (tid >> 4) << 2, c0 = (tid & 15) << 2;
  float acc[4][4] = {};
  float rowS = (TRA == TR_SCALEROW) ? rowScale[ar] : 1.f;

  for (int kb = kB; kb < kE; kb += BK) {
    {
      const float* Ap = A + (long)ar * lda + kb + ak;
      float v[8];
      if (kb + ak + 7 < kE) {
        float4 u0 = *(const float4*)(Ap);
        float4 u1 = *(const float4*)(Ap + 4);
        v[0] = u0.x; v[1] = u0.y; v[2] = u0.z; v[3] = u0.w;
        v[4] = u1.x; v[5] = u1.y; v[6] = u1.z; v[7] = u1.w;
      } else {
#pragma unroll
        for (int i = 0; i < 8; i++) v[i] = (kb + ak + i < kE) ? Ap[i] : 0.f;
      }
#pragma unroll
      for (int i = 0; i < 8; i++) {
        float x = (kb + ak + i < kE) ? v[i] : 0.f;
        if (TRA == TR_SCALEROW) x *= rowS;
        As[ak + i][ar] = x;
      }
    }
    {
      int k = kb + bk;
      const float* Bp = B + (long)k * ldb + cBase + bc;
      if (k < kE && cBase + bc + 7 < N) {
        float4 u0 = *(const float4*)(Bp);
        float4 u1 = *(const float4*)(Bp + 4);
        Bs[bk][bc + 0] = u0.x; Bs[bk][bc + 1] = u0.y;
        Bs[bk][bc + 2] = u0.z; Bs[bk][bc + 3] = u0.w;
        Bs[bk][bc + 4] = u1.x; Bs[bk][bc + 5] = u1.y;
        Bs[bk][bc + 6] = u1.z; Bs[bk][bc + 7] = u1.w;
      } else {
#pragma unroll
        for (int i = 0; i < 8; i++)
          Bs[bk][bc + i] = (k < kE && cBase + bc + i < N) ? Bp[i] : 0.f;
      }
    }
    __syncthreads();
#pragma unroll
    for (int kk = 0; kk < BK; kk++) {
      float4 a4 = *(const float4*)&As[kk][r0];
      float4 b4 = *(const float4*)&Bs[kk][c0];
      float av[4] = {a4.x, a4.y, a4.z, a4.w};
      float bv[4] = {b4.x, b4.y, b4.z, b4.w};
#pragma unroll
      for (int i = 0; i < 4; i++)
#pragma unroll
        for (int j = 0; j < 4; j++) acc[i][j] += av[i] * bv[j];
    }
    __syncthreads();
  }

#pragma unroll
  for (int i = 0; i < 4; i++) {
    float4 v = make_float4(acc[i][0], acc[i][1], acc[i][2], acc[i][3]);
    int c = cBase + c0;
    if (baseAdd) {
      const float* bp = baseAdd + (long)(r0 + i) * 1024 + c;
      v.x += (c + 0 < N) ? bp[0] : 0.f;
      v.y += (c + 1 < N) ? bp[1] : 0.f;
      v.z += (c + 2 < N) ? bp[2] : 0.f;
      v.w += (c + 3 < N) ? bp[3] : 0.f;
    }
    if (colBias) {
      v.x += (c + 0 < N) ? colBias[c + 0] : 0.f;
      v.y += (c + 1 < N) ? colBias[c + 1] : 0.f;
      v.z += (c + 2 < N) ? colBias[c + 2] : 0.f;
      v.w += (c + 3 < N) ? colBias[c + 3] : 0.f;
    }
    *(float4*)&C[(long)(r0 + i) * ldc + cBase + c0] = v;
  }
}

// Sum nParts partials for row r, LN(1000)+ELU, write transformed row (pad=0).
__device__ void phase_fin(const float* parts, int nParts, long pStride,
                          const float* g, const float* bta, float* out, int r,
                          float* red) {
  const int tid = threadIdx.x;
  float v[4];
  float s = 0.f, sq = 0.f;
#pragma unroll
  for (int i = 0; i < 4; i++) {
    int c = tid + (i << 8);
    float x = 0.f;
    for (int p = 0; p < nParts; p++) x += parts[p * pStride + (long)r * 1024 + c];
    v[i] = x;
    if (c < 1000) { s += x; sq += x * x; }
  }
#pragma unroll
  for (int off = 32; off >= 1; off >>= 1) {
    s += __shfl_down(s, off);
    sq += __shfl_down(sq, off);
  }
  if ((tid & 63) == 0) { red[tid >> 6] = s; red[4 + (tid >> 6)] = sq; }
  __syncthreads();
  if (tid == 0) {
    float S = red[0] + red[1] + red[2] + red[3];
    float Q = red[4] + red[5] + red[6] + red[7];
    float mean = S / 1000.f;
    float var = Q / 1000.f - mean * mean;
    red[8] = mean;
    red[9] = 1.f / sqrtf(var + 1e-3f);
  }
  __syncthreads();
  float mean = red[8], rstd = red[9];
#pragma unroll
  for (int i = 0; i < 4; i++) {
    int c = tid + (i << 8);
    float y = 0.f;
    if (c < 1000) {
      y = (v[i] - mean) * rstd * g[c] + bta[c];
      y = y > 0.f ? y : expm1f(y);
    }
    out[(long)r * 1024 + c] = y;
  }
  __syncthreads();
}

__device__ void phase_gates(const ScanArgs& a, const float* hprev, int ldh,
                            const float* mk, float* feat_t, int t) {
  int i = blockIdx.x * 256 + threadIdx.x;  // 0..131071
  int b = i >> 11, d = i & 2047;
  long gio = (long)b * 6144 + d;
  float gir = 0.f, giz = 0.f, gin = 0.f;
#pragma unroll
  for (int p = 0; p < 5; p++) {
    long o = (long)p * 393216 + gio;
    gir += a.gi_parts[o]; giz += a.gi_parts[o + 2048]; gin += a.gi_parts[o + 4096];
  }
  gir += a.gbi[d]; giz += a.gbi[d + 2048]; gin += a.gbi[d + 4096];
  float ghr = a.gbh[d], ghz = a.gbh[d + 2048], ghn = a.gbh[d + 4096];
#pragma unroll
  for (int p = 0; p < 8; p++) {
    long o = (long)p * 393216 + gio;
    ghr += a.gh_parts[o]; ghz += a.gh_parts[o + 2048]; ghn += a.gh_parts[o + 4096];
  }
  float r = sigm(gir + ghr);
  float u = sigm(giz + ghz);
  float n = xla_tanh(gin + r * ghn);
  float hm = hprev[(long)b * ldh + d] * mk[b];
  float h = (1.f - u) * n + u * hm;
  feat_t[(long)b * 3072 + d] = h;
  if (t == 63) a.hlast[(long)b * 2048 + d] = h;
}

__device__ void phase_sample(const ScanArgs& a, int t, float* feat_t) {
  int gid = blockIdx.x * 256 + threadIdx.x;  // blockIdx < 256 -> gid 0..65535
  int b = gid >> 10, sj = gid & 1023, j = gid & 31;
  float v = 0.f;
#pragma unroll
  for (int p = 0; p < 8; p++) v += a.pp_parts[(long)p * 65536 + (long)b * 1024 + sj];
  a.posts[(long)t * 65536 + (long)b * 1024 + sj] = v;
  uint2 kt = threefry(0u, 42u, 0u, (unsigned)t);
  unsigned idx = (unsigned)(b * 1024 + sj);
  uint2 o = threefry(kt.x, kt.y, 0u, idx);
  unsigned bits = o.x ^ o.y;
  const float TINY = 1.175494350822287508e-38f;
  float u = __uint_as_float((bits >> 9) | 0x3f800000u) - 1.0f;
  u = fmaxf(TINY, u + TINY);
  float sc = v + -logf(-logf(u));
  float bs = sc;
  int bj = j;
#pragma unroll
  for (int off = 16; off >= 1; off >>= 1) {
    float os = __shfl_xor(bs, off, 32);
    int oj = __shfl_xor(bj, off, 32);
    if (os > bs || (os == bs && oj < bj)) { bs = os; bj = oj; }
  }
  float oh = (j == bj) ? 1.f : 0.f;
  a.samples[(long)t * 65536 + (long)b * 1024 + sj] = oh;
  feat_t[(long)b * 3072 + 2048 + sj] = oh;
  if (t == 63) a.zlast[b * 1024 + sj] = oh;
}

__global__ __launch_bounds__(256, 2) void k_scan(ScanArgs a) {
  __shared__ float As[BK][LDP];
  __shared__ float Bs[BK][LDP];
  __shared__ float red[16];
  unsigned lgen = 0;
  const int bid = blockIdx.x;

  // Prologue: gh(0) = (h0*m0) @ gru_wh, 8 K-chunks of 256 in two halves.
  for (int half = 0; half < 2; half++) {
    if (bid >= 128) {
      int idx = bid - 128;
      int tile = idx % 96, ks = half * 4 + idx / 96;
      phase_gemm<TR_SCALEROW>(As, Bs, a.h0, 2048, a.gwh, 6144, ks * 256,
                              ks * 256 + 256, tile * 64, 6144, a.mask,
                              a.gh_parts + (long)ks * 393216, 6144, nullptr, nullptr);
    }
    gridbar(a.bar, lgen);
  }

  for (int t = 0; t < 64; t++) {
    const float* z = t ? a.samples + (long)(t - 1) * 65536 : a.z0;
    const float* hprev = t ? a.feats + (long)(t - 1) * 196608 : a.h0;
    int ldh = t ? 3072 : 2048;
    const float* mk = a.mask + t * 64;
    float* feat_t = a.feats + (long)t * 196608;

    // P1: xa partials = (z*m) @ zw  (+ xa_base at ks==0)
    {
      int ct = bid & 15, ks = bid >> 4;  // 16 col tiles x 32 K-chunks
      phase_gemm<TR_SCALEROW>(As, Bs, z, 1024, a.zw, 1000, ks * 32, ks * 32 + 32,
                              ct * 64, 1000, mk, a.xa_parts + (long)ks * 65536,
                              1024, (ks == 0) ? a.xa_base + (long)t * 65536 : nullptr,
                              nullptr);
    }
    gridbar(a.bar, lgen);

    // P2: xe = elu(ln(sum parts))
    if (bid < 64) phase_fin(a.xa_parts, 32, 65536, a.in_g, a.in_b, a.xe, bid, red);
    gridbar(a.bar, lgen);

    // P3: gi partials = xe @ gru_wi
    if (bid < 480) {
      int tile = bid % 96, ks = bid / 96;  // 96 tiles x 5 K-chunks of 200
      phase_gemm<TR_NONE>(As, Bs, a.xe, 1024, a.gwi, 6144, ks * 200, ks * 200 + 200,
                          tile * 64, 6144, nullptr, a.gi_parts + (long)ks * 393216,
                          6144, nullptr, nullptr);
    }
    gridbar(a.bar, lgen);

    // P4: GRU gates -> h_t (into feats[t])
    phase_gates(a, hprev, ldh, mk, feat_t, t);
    gridbar(a.bar, lgen);

    // P5: x2 partials = h_t @ ph_w (+x2_base)  ||  gh(t+1) chunks 0..3
    if (bid < 128) {
      int ct = bid & 15, ks = bid >> 4;  // 8 chunks of 256
      phase_gemm<TR_NONE>(As, Bs, feat_t, 3072, a.ph_w, 1000, ks * 256,
                          ks * 256 + 256, ct * 64, 1000, nullptr,
                          a.x2_parts + (long)ks * 65536, 1024,
                          (ks == 0) ? a.x2_base + (long)t * 65536 : nullptr, nullptr);
    } else if (t < 63) {
      int idx = bid - 128;
      int tile = idx % 96, ks = idx / 96;
      phase_gemm<TR_SCALEROW>(As, Bs, feat_t, 3072, a.gwh, 6144, ks * 256,
                              ks * 256 + 256, tile * 64, 6144, a.mask + (t + 1) * 64,
                              a.gh_parts + (long)ks * 393216, 6144, nullptr, nullptr);
    }
    gridbar(a.bar, lgen);

    // P6: x2e = elu(ln(sum parts))
    if (bid < 64) phase_fin(a.x2_parts, 8, 65536, a.po_g, a.po_b, a.x2e, bid, red);
    gridbar(a.bar, lgen);

    // P7: pp partials = x2e @ pp_w (+pp_b)  ||  gh(t+1) chunks 4..7
    if (bid < 128) {
      int ct = bid & 15, ks = bid >> 4;  // 8 chunks of 128 (last=104)
      int kB = ks * 128, kE = min(1000, kB + 128);
      phase_gemm<TR_NONE>(As, Bs, a.x2e, 1024, a.pp_w, 1024, kB, kE, ct * 64, 1024,
                          nullptr, a.pp_parts + (long)ks * 65536, 1024, nullptr,
                          (ks == 0) ? a.pp_b : nullptr);
    } else if (t < 63) {
      int idx = bid - 128;
      int tile = idx % 96, ks = 4 + idx / 96;
      phase_gemm<TR_SCALEROW>(As, Bs, feat_t, 3072, a.gwh, 6144, ks * 256,
                              ks * 256 + 256, tile * 64, 6144, a.mask + (t + 1) * 64,
                              a.gh_parts + (long)ks * 393216, 6144, nullptr, nullptr);
    }
    gridbar(a.bar, lgen);

    // P8: posts/sample/one-hot -> samples, feats z-section
    if (bid < 256) phase_sample(a, t, feat_t);
    gridbar(a.bar, lgen);
  }
}

// ======================= small helper kernels ==============================
__global__ void k_init(unsigned* bar) {
  if (threadIdx.x < 16) bar[threadIdx.x] = 0u;
}

__global__ void k_detect(const unsigned* rr, int nDwordsSafe, int* fmt) {
  __shared__ int flags;
  if (threadIdx.x == 0) flags = 0;
  __syncthreads();
  int local = 0;
  for (int i = threadIdx.x; i < nDwordsSafe; i += 256) {
    unsigned dw = rr[i];
    if (dw == 0x3f800000u) local |= 4;
    else if (dw & 0xFFFFFF00u) local |= 1;
    else if (dw == 1u) local |= 2;
  }
  atomicOr(&flags, local);
  __syncthreads();
  if (threadIdx.x == 0) {
    int f = flags;
    *fmt = ((f & 4) == 0 && (f & 1)) ? 1 : 0;
  }
}

__global__ void k_prep(const void* rr, const int* fmt, float* mask, int n) {
  int i = blockIdx.x * 256 + threadIdx.x;
  if (i < n) {
    bool reset;
    if (*fmt == 1) reset = ((const unsigned char*)rr)[i] != 0;
    else reset = ((const int*)rr)[i] != 0;
    mask[i] = reset ? 0.0f : 1.0f;
  }
}

// xa_base[row][c] = sum_k actions[row][k]*aw[k][c] + zb[c]  (c<1000; pad 0)
__global__ __launch_bounds__(256) void k_abase(const float* act, const float* aw,
                                               const float* zb, float* out) {
  for (long i = blockIdx.x * 256L + threadIdx.x; i < 4096L * 1024;
       i += (long)gridDim.x * 256) {
    int row = (int)(i >> 10), c = (int)(i & 1023);
    float v = 0.f;
    if (c < 1000) {
      v = zb[c];
#pragma unroll
      for (int k = 0; k < 6; k++) v += act[row * 6 + k] * aw[k * 1000 + c];
    }
    out[i] = v;
  }
}

// ---------------------------------------------------------------------------
extern "C" void kernel_launch(void* const* d_in, const int* in_sizes, int n_in,
                              void* d_out, int out_size, void* d_ws, size_t ws_size,
                              hipStream_t stream) {
  const float* embeds = (const float*)d_in[0];
  const float* actions = (const float*)d_in[1];
  const void* resets = d_in[2];
  const float* h0 = (const float*)d_in[3];
  const float* z0 = (const float*)d_in[4];
  const float* zw = (const float*)d_in[5];
  const float* zb = (const float*)d_in[6];
  const float* aw = (const float*)d_in[7];
  const float* in_g = (const float*)d_in[8];
  const float* in_b = (const float*)d_in[9];
  const float* gwi = (const float*)d_in[10];
  const float* gwh = (const float*)d_in[11];
  const float* gbi = (const float*)d_in[12];
  const float* gbh = (const float*)d_in[13];
  const float* ph_w = (const float*)d_in[14];
  const float* ph_b = (const float*)d_in[15];
  const float* pe_w = (const float*)d_in[16];
  const float* po_g = (const float*)d_in[17];
  const float* po_b = (const float*)d_in[18];
  const float* pp_w = (const float*)d_in[19];
  const float* pp_b = (const float*)d_in[20];
  const float* prh_w = (const float*)d_in[21];
  const float* prh_b = (const float*)d_in[22];
  const float* pr_g = (const float*)d_in[23];
  const float* pr_b = (const float*)d_in[24];
  const float* prp_w = (const float*)d_in[25];
  const float* prp_b = (const float*)d_in[26];

  float* out = (float*)d_out;
  float* priors  = out;
  float* posts   = out + 4194304;
  float* samples = out + 8388608;
  float* feats   = out + 12582912;
  float* hlast   = out + 25165824;
  float* zlast   = out + 25296896;

  float* ws = (float*)d_ws;
  unsigned* bar   = (unsigned*)ws;            // [0..15]
  int*   fmt      = (int*)(ws + 16);
  float* mask     = ws + 64;                  // 4096
  float* stats_p  = ws + 4160;                // 8192
  float* xe       = ws + 12352;               // 65536
  float* x2e      = ws + 77888;               // 65536
  float* xa_parts = ws + 143424;              // 32*65536 = 2097152
  float* gi_parts = ws + 2240576;             // 5*393216 = 1966080
  float* gh_parts = ws + 4206656;             // 8*393216 = 3145728
  float* x2_parts = ws + 7352384;             // 8*65536  = 524288
  float* pp_parts = ws + 7876672;             // 8*65536  = 524288
  float* xa_base  = ws + 8400960;             // 4194304
  float* x2_base  = ws + 12595264;            // 4194304
  float* xp       = ws + 16789568;            // 4194304  (end 20983872 fl = 84MB)

  k_init<<<1, 64, 0, stream>>>(bar);
  k_detect<<<1, 256, 0, stream>>>((const unsigned*)resets, 1024, fmt);
  k_prep<<<16, 256, 0, stream>>>(resets, fmt, mask, 4096);
  k_abase<<<2048, 256, 0, stream>>>(actions, aw, zb, xa_base);

  // x2_base = embeds @ pe_w + ph_b (batched 4096x1000, K=1024)
  GemmArgs ge{};
  ge.A = embeds; ge.lda = 1024; ge.B = pe_w; ge.ldb = 1000; ge.K = 1024; ge.ksplit = 1;
  ge.N = 1000; ge.bias = ph_b; ge.C = x2_base; ge.ldc = 1024; ge.partStride = 0;
  k_gemm<TR_NONE, TR_NONE><<<dim3(16, 1, 64), 256, 0, stream>>>(ge);

  // persistent 64-step scan
  ScanArgs sa{};
  sa.z0 = z0; sa.h0 = h0; sa.zw = zw; sa.gwi = gwi; sa.gwh = gwh;
  sa.gbi = gbi; sa.gbh = gbh; sa.ph_w = ph_w; sa.pp_w = pp_w; sa.pp_b = pp_b;
  sa.in_g = in_g; sa.in_b = in_b; sa.po_g = po_g; sa.po_b = po_b;
  sa.mask = mask; sa.xa_base = xa_base; sa.x2_base = x2_base;
  sa.xa_parts = xa_parts; sa.gi_parts = gi_parts; sa.gh_parts = gh_parts;
  sa.x2_parts = x2_parts; sa.pp_parts = pp_parts; sa.xe = xe; sa.x2e = x2e;
  sa.posts = posts; sa.samples = samples; sa.feats = feats;
  sa.hlast = hlast; sa.zlast = zlast; sa.bar = bar;
  k_scan<<<NBLK, 256, 0, stream>>>(sa);

  // prior head (batched over all T*B rows)
  GemmArgs gp1{};
  gp1.A = feats; gp1.lda = 3072; gp1.B = prh_w; gp1.ldb = 1000; gp1.K = 2048; gp1.ksplit = 1;
  gp1.N = 1000; gp1.bias = prh_b; gp1.C = xp; gp1.ldc = 1024; gp1.partStride = 0;
  k_gemm<TR_NONE, TR_NONE><<<dim3(16, 1, 64), 256, 0, stream>>>(gp1);
  k_prstat<<<1024, 256, 0, stream>>>(xp, stats_p, 1000);
  GemmArgs gp2{};
  gp2.A = xp; gp2.lda = 1024; gp2.B = prp_w; gp2.ldb = 1024; gp2.K = 1000; gp2.ksplit = 1;
  gp2.N = 1024; gp2.bias = prp_b; gp2.t1s = stats_p; gp2.t1g = pr_g; gp2.t1b = pr_b;
  gp2.C = priors; gp2.ldc = 1024; gp2.partStride = 0;
  k_gemm<TR_LNELU, TR_NONE><<<dim3(16, 1, 64), 256, 0, stream>>>(gp2);
}

// Round 3
// 19416.164 us; speedup vs baseline: 4.2504x; 4.2504x over previous
//
#include <hip/hip_runtime.h>
#include <hip/hip_bf16.h>

// ---------------------------------------------------------------------------
// RSSMCore persistent-scan v2.
// R2 lesson: agent-scope fences/acquires = full-L2 inv/wb per op on gfx950
// (non-coherent per-XCD L2s) -> 157us/barrier. Fix: relaxed-only barrier and
// ALL mutable cross-phase data via system-scope (sc0 sc1, L2-bypass) atomic
// load/store; weights stay normally cached (L2-hot across steps).
// Also: z(t>=1) is exactly one-hot -> z@zw becomes a 32-row gather of zw,
// fused with LN+ELU in one phase (7 phases/step, was 8+fin).
// ---------------------------------------------------------------------------

#define BK 32
#define LDP 66
#define NBLK 512

enum { TR_NONE = 0, TR_SCALEROW = 1, TR_LNELU = 2 };

// ---------------- coherent (L2-bypassing) access helpers -------------------
__device__ inline float cload(const float* p) {
  return __hip_atomic_load(p, __ATOMIC_RELAXED, __HIP_MEMORY_SCOPE_SYSTEM);
}
__device__ inline void cstore(float* p, float v) {
  __hip_atomic_store(p, v, __ATOMIC_RELAXED, __HIP_MEMORY_SCOPE_SYSTEM);
}
__device__ inline float2 cload2(const float* p) {
  unsigned long long u = __hip_atomic_load((const unsigned long long*)p,
                                           __ATOMIC_RELAXED, __HIP_MEMORY_SCOPE_SYSTEM);
  float2 r;
  r.x = __uint_as_float((unsigned)u);
  r.y = __uint_as_float((unsigned)(u >> 32));
  return r;
}
__device__ inline void cstore2(float* p, float x, float y) {
  unsigned long long u =
      ((unsigned long long)__float_as_uint(y) << 32) | (unsigned long long)__float_as_uint(x);
  __hip_atomic_store((unsigned long long*)p, u, __ATOMIC_RELAXED, __HIP_MEMORY_SCOPE_SYSTEM);
}
__device__ inline int cloadi(const int* p) {
  return __hip_atomic_load(p, __ATOMIC_RELAXED, __HIP_MEMORY_SCOPE_SYSTEM);
}
__device__ inline void cstorei(int* p, int v) {
  __hip_atomic_store(p, v, __ATOMIC_RELAXED, __HIP_MEMORY_SCOPE_SYSTEM);
}

// XLA f32 tanh rational approximation (mul/add, no contraction) -------------
__device__ inline float xla_tanh(float x) {
  float ax = fabsf(x);
  float xc = fminf(fmaxf(x, -7.90531110763549805f), 7.90531110763549805f);
  float x2 = __fmul_rn(xc, xc);
  float p = -2.76076847742355e-16f;
  p = __fadd_rn(__fmul_rn(p, x2), 2.00018790482477e-13f);
  p = __fadd_rn(__fmul_rn(p, x2), -8.60467152213735e-11f);
  p = __fadd_rn(__fmul_rn(p, x2), 5.12229709037114e-08f);
  p = __fadd_rn(__fmul_rn(p, x2), 1.48572235717979e-05f);
  p = __fadd_rn(__fmul_rn(p, x2), 6.37261928875436e-04f);
  p = __fadd_rn(__fmul_rn(p, x2), 4.89352455891786e-03f);
  float num = __fmul_rn(xc, p);
  float q = 1.19825839466702e-06f;
  q = __fadd_rn(__fmul_rn(q, x2), 1.18534705686654e-04f);
  q = __fadd_rn(__fmul_rn(q, x2), 2.26843463243900e-03f);
  q = __fadd_rn(__fmul_rn(q, x2), 4.89352518554385e-03f);
  float r = __fdiv_rn(num, q);
  return ax < 0.0004f ? x : r;
}

__device__ inline float sigm(float x) { return 1.0f / (1.0f + expf(-x)); }

// Threefry2x32 (20 rounds), matches jax/_src/prng.py ------------------------
__device__ inline void tfround(unsigned& x0, unsigned& x1, int r) {
  x0 += x1; x1 = (x1 << r) | (x1 >> (32 - r)); x1 ^= x0;
}
__device__ inline uint2 threefry(unsigned k0, unsigned k1, unsigned c0, unsigned c1) {
  unsigned ks2 = k0 ^ k1 ^ 0x1BD11BDAu;
  unsigned x0 = c0 + k0, x1 = c1 + k1;
  tfround(x0, x1, 13); tfround(x0, x1, 15); tfround(x0, x1, 26); tfround(x0, x1, 6);
  x0 += k1; x1 += ks2 + 1u;
  tfround(x0, x1, 17); tfround(x0, x1, 29); tfround(x0, x1, 16); tfround(x0, x1, 24);
  x0 += ks2; x1 += k0 + 2u;
  tfround(x0, x1, 13); tfround(x0, x1, 15); tfround(x0, x1, 26); tfround(x0, x1, 6);
  x0 += k0; x1 += k1 + 3u;
  tfround(x0, x1, 17); tfround(x0, x1, 29); tfround(x0, x1, 16); tfround(x0, x1, 24);
  x0 += k1; x1 += ks2 + 4u;
  tfround(x0, x1, 13); tfround(x0, x1, 15); tfround(x0, x1, 26); tfround(x0, x1, 6);
  x0 += ks2; x1 += k0 + 5u;
  return make_uint2(x0, x1);
}

// ======================= round-1 proven tiled GEMM (pre/post) ==============
struct GemmArgs {
  const float* A; int lda; const float* B; int ldb; int K; int ksplit;
  const float* A2; int lda2; const float* B2; int ldb2; int K2;
  int N; const float* bias;
  const float* t1s; const float* t1g; const float* t1b;
  float* C; int ldc; long partStride;
};

template <int TRA>
__device__ void gemm_tiles(float acc[4][4], float (*As)[LDP], float (*Bs)[LDP],
                           const float* A, int lda, const float* B, int ldb,
                           int kB, int kE, int mBase, int cBase, int N,
                           const float* s0, const float* g0, const float* b0) {
  const int tid = threadIdx.x;
  const int ar = tid >> 2;
  const int ak = (tid & 3) << 3;
  const int bk = tid >> 3;
  const int bc = (tid & 7) << 3;
  const int r0 = (tid >> 4) << 2;
  const int c0 = (tid & 15) << 2;

  float rowS = 1.f, rowM = 0.f, rowR = 1.f;
  if (TRA == TR_SCALEROW) rowS = s0[mBase + ar];
  else if (TRA == TR_LNELU) {
    rowM = s0[(mBase + ar) * 2];
    rowR = s0[(mBase + ar) * 2 + 1];
  }

  for (int kb = kB; kb < kE; kb += BK) {
    {
      const float* Ap = A + (long)(mBase + ar) * lda + kb + ak;
      float v[8];
      if (kb + ak + 7 < kE) {
        float4 u0 = *(const float4*)(Ap);
        float4 u1 = *(const float4*)(Ap + 4);
        v[0] = u0.x; v[1] = u0.y; v[2] = u0.z; v[3] = u0.w;
        v[4] = u1.x; v[5] = u1.y; v[6] = u1.z; v[7] = u1.w;
      } else {
#pragma unroll
        for (int i = 0; i < 8; i++) v[i] = (kb + ak + i < kE) ? Ap[i] : 0.f;
      }
#pragma unroll
      for (int i = 0; i < 8; i++) {
        int k = kb + ak + i;
        float x = 0.f;
        if (k < kE) {
          x = v[i];
          if (TRA == TR_SCALEROW) {
            x *= rowS;
          } else if (TRA == TR_LNELU) {
            x = (x - rowM) * rowR * g0[k] + b0[k];
            x = x > 0.f ? x : expm1f(x);
          }
        }
        As[ak + i][ar] = x;
      }
    }
    {
      int k = kb + bk;
      const float* Bp = B + (long)k * ldb + cBase + bc;
      if (k < kE && cBase + bc + 7 < N) {
        float4 u0 = *(const float4*)(Bp);
        float4 u1 = *(const float4*)(Bp + 4);
        Bs[bk][bc + 0] = u0.x; Bs[bk][bc + 1] = u0.y;
        Bs[bk][bc + 2] = u0.z; Bs[bk][bc + 3] = u0.w;
        Bs[bk][bc + 4] = u1.x; Bs[bk][bc + 5] = u1.y;
        Bs[bk][bc + 6] = u1.z; Bs[bk][bc + 7] = u1.w;
      } else {
#pragma unroll
        for (int i = 0; i < 8; i++)
          Bs[bk][bc + i] = (k < kE && cBase + bc + i < N) ? Bp[i] : 0.f;
      }
    }
    __syncthreads();
#pragma unroll
    for (int kk = 0; kk < BK; kk++) {
      float4 a4 = *(const float4*)&As[kk][r0];
      float4 b4 = *(const float4*)&Bs[kk][c0];
      float av[4] = {a4.x, a4.y, a4.z, a4.w};
      float bv[4] = {b4.x, b4.y, b4.z, b4.w};
#pragma unroll
      for (int i = 0; i < 4; i++)
#pragma unroll
        for (int j = 0; j < 4; j++) acc[i][j] += av[i] * bv[j];
    }
    __syncthreads();
  }
}

template <int TRA, int TRA2>
__global__ __launch_bounds__(256) void k_gemm(GemmArgs g) {
  __shared__ float As[BK][LDP];
  __shared__ float Bs[BK][LDP];
  const int nT = blockIdx.x, ks = blockIdx.y, mT = blockIdx.z;
  const int mBase = mT * 64, cBase = nT * 64;
  float acc[4][4] = {};
  int chunk = (((g.K + g.ksplit - 1) / g.ksplit) + 31) & ~31;
  int kB = ks * chunk, kE = min(g.K, kB + chunk);
  if (kB < kE)
    gemm_tiles<TRA>(acc, As, Bs, g.A, g.lda, g.B, g.ldb, kB, kE, mBase, cBase,
                    g.N, g.t1s, g.t1g, g.t1b);
  if (g.A2) {
    int chunk2 = (((g.K2 + g.ksplit - 1) / g.ksplit) + 31) & ~31;
    int kB2 = ks * chunk2, kE2 = min(g.K2, kB2 + chunk2);
    if (kB2 < kE2)
      gemm_tiles<TRA2>(acc, As, Bs, g.A2, g.lda2, g.B2, g.ldb2, kB2, kE2, mBase,
                       cBase, g.N, nullptr, nullptr, nullptr);
  }
  const int tid = threadIdx.x;
  const int r0 = (tid >> 4) << 2, c0 = (tid & 15) << 2;
  float* Cb = g.C + (long)ks * g.partStride;
#pragma unroll
  for (int i = 0; i < 4; i++) {
    float4 v = make_float4(acc[i][0], acc[i][1], acc[i][2], acc[i][3]);
    if (ks == 0 && g.bias) {
      int c = cBase + c0;
      v.x += (c + 0 < g.N) ? g.bias[c + 0] : 0.f;
      v.y += (c + 1 < g.N) ? g.bias[c + 1] : 0.f;
      v.z += (c + 2 < g.N) ? g.bias[c + 2] : 0.f;
      v.w += (c + 3 < g.N) ? g.bias[c + 3] : 0.f;
    }
    *(float4*)&Cb[(long)(mBase + r0 + i) * g.ldc + cBase + c0] = v;
  }
}

__global__ __launch_bounds__(256) void k_prstat(const float* xp, float* stats, int N) {
  int wave = threadIdx.x >> 6, lane = threadIdx.x & 63;
  int r = blockIdx.x * 4 + wave;
  float s = 0.f, sq = 0.f;
  for (int c = lane; c < N; c += 64) {
    float v = xp[(long)r * 1024 + c];
    s += v; sq += v * v;
  }
#pragma unroll
  for (int off = 32; off >= 1; off >>= 1) {
    s += __shfl_down(s, off);
    sq += __shfl_down(sq, off);
  }
  if (lane == 0) {
    float mean = s / N, var = sq / N - mean * mean;
    stats[r * 2] = mean;
    stats[r * 2 + 1] = 1.0f / sqrtf(var + 1e-3f);
  }
}

// ======================= persistent scan kernel ============================
struct ScanArgs {
  const float* h0;
  const float* zw; const float* gwi; const float* gwh;
  const float* gbi; const float* gbh;
  const float* ph_w; const float* pp_w; const float* pp_b;
  const float* in_g; const float* in_b; const float* po_g; const float* po_b;
  const float* mask;
  const float* xa_base; const float* x2_base; const float* xa_t0;
  float* gi_parts; float* gh_parts; float* x2_parts; float* pp_parts;
  float* xe; float* x2e; int* idx;
  float* posts; float* samples; float* feats; float* hlast; float* zlast;
  unsigned* bar;  // cells at [c*32], root at [256], gen at [288]
};

// Relaxed-only two-level grid barrier: NO fences, NO acquire (each agent
// acquire = full L2 inv on gfx950 -> R2's 157us/barrier disaster).
// Visibility: all shared data uses sc0sc1 accesses; vmcnt(0) before arrival
// guarantees our write-through stores reached the coherence point.
__device__ inline void gridbar(unsigned* bar, unsigned& lgen) {
  asm volatile("s_waitcnt vmcnt(0)" ::: "memory");
  __syncthreads();
  lgen++;
  if (threadIdx.x == 0) {
    int cell = (blockIdx.x & 7) * 32;
    unsigned prev = __hip_atomic_fetch_add(&bar[cell], 1u, __ATOMIC_RELAXED,
                                           __HIP_MEMORY_SCOPE_AGENT);
    if (prev == 64u * lgen - 1u) {  // last of this cell's 64 members
      unsigned p2 = __hip_atomic_fetch_add(&bar[256], 1u, __ATOMIC_RELAXED,
                                           __HIP_MEMORY_SCOPE_AGENT);
      if (p2 == 8u * lgen - 1u)
        __hip_atomic_store(&bar[288], lgen, __ATOMIC_RELAXED,
                           __HIP_MEMORY_SCOPE_AGENT);
    }
    while (__hip_atomic_load(&bar[288], __ATOMIC_RELAXED,
                             __HIP_MEMORY_SCOPE_AGENT) < lgen)
      __builtin_amdgcn_s_sleep(16);
  }
  __syncthreads();
}

// 64x64 tile GEMM, one K-chunk, M=64 rows. A read coherently, B cached.
template <int TRA>
__device__ void phase_gemm(float (*As)[LDP], float (*Bs)[LDP],
                           const float* A, int lda, const float* B, int ldb,
                           int kB, int kE, int cBase, int N,
                           const float* rowScale, float* C, int ldc,
                           const float* baseAdd, const float* colBias) {
  const int tid = threadIdx.x;
  const int ar = tid >> 2, ak = (tid & 3) << 3;
  const int bk = tid >> 3, bc = (tid & 7) << 3;
  const int r0 = (tid >> 4) << 2, c0 = (tid & 15) << 2;
  float acc[4][4] = {};
  float rowS = (TRA == TR_SCALEROW) ? rowScale[ar] : 1.f;

  for (int kb = kB; kb < kE; kb += BK) {
    float v[8];
    {
      const float* Ap = A + (long)ar * lda + kb + ak;
      if (kb + ak + 7 < kE) {
#pragma unroll
        for (int i = 0; i < 4; i++) {
          float2 u = cload2(Ap + 2 * i);
          v[2 * i] = u.x; v[2 * i + 1] = u.y;
        }
      } else {
#pragma unroll
        for (int i = 0; i < 8; i++) v[i] = (kb + ak + i < kE) ? cload(Ap + i) : 0.f;
      }
    }
    float w[8];
    {
      int k = kb + bk;
      const float* Bp = B + (long)k * ldb + cBase + bc;
      if (k < kE && cBase + bc + 7 < N) {
        float4 u0 = *(const float4*)(Bp);
        float4 u1 = *(const float4*)(Bp + 4);
        w[0] = u0.x; w[1] = u0.y; w[2] = u0.z; w[3] = u0.w;
        w[4] = u1.x; w[5] = u1.y; w[6] = u1.z; w[7] = u1.w;
      } else {
#pragma unroll
        for (int i = 0; i < 8; i++)
          w[i] = (k < kE && cBase + bc + i < N) ? Bp[i] : 0.f;
      }
    }
#pragma unroll
    for (int i = 0; i < 8; i++)
      As[ak + i][ar] = (TRA == TR_SCALEROW) ? v[i] * rowS : v[i];
#pragma unroll
    for (int i = 0; i < 8; i++) Bs[bk][bc + i] = w[i];
    __syncthreads();
#pragma unroll
    for (int kk = 0; kk < BK; kk++) {
      float4 a4 = *(const float4*)&As[kk][r0];
      float4 b4 = *(const float4*)&Bs[kk][c0];
      float av[4] = {a4.x, a4.y, a4.z, a4.w};
      float bv[4] = {b4.x, b4.y, b4.z, b4.w};
#pragma unroll
      for (int i = 0; i < 4; i++)
#pragma unroll
        for (int j = 0; j < 4; j++) acc[i][j] += av[i] * bv[j];
    }
    __syncthreads();
  }

#pragma unroll
  for (int i = 0; i < 4; i++) {
    float4 v4 = make_float4(acc[i][0], acc[i][1], acc[i][2], acc[i][3]);
    int c = cBase + c0;
    if (baseAdd) {
      const float* bp = baseAdd + (long)(r0 + i) * 1024 + c;
      v4.x += (c + 0 < N) ? bp[0] : 0.f;
      v4.y += (c + 1 < N) ? bp[1] : 0.f;
      v4.z += (c + 2 < N) ? bp[2] : 0.f;
      v4.w += (c + 3 < N) ? bp[3] : 0.f;
    }
    if (colBias) {
      v4.x += (c + 0 < N) ? colBias[c + 0] : 0.f;
      v4.y += (c + 1 < N) ? colBias[c + 1] : 0.f;
      v4.z += (c + 2 < N) ? colBias[c + 2] : 0.f;
      v4.w += (c + 3 < N) ? colBias[c + 3] : 0.f;
    }
    float* Cp = &C[(long)(r0 + i) * ldc + cBase + c0];
    cstore2(Cp, v4.x, v4.y);
    cstore2(Cp + 2, v4.z, v4.w);
  }
}

// Block-wide LN helper: v[4] per thread (cols tid, tid+256, ...), N=1000.
__device__ inline void ln_reduce(float s, float sq, float* red, float& mean,
                                 float& rstd) {
  const int tid = threadIdx.x;
#pragma unroll
  for (int off = 32; off >= 1; off >>= 1) {
    s += __shfl_down(s, off);
    sq += __shfl_down(sq, off);
  }
  if ((tid & 63) == 0) { red[tid >> 6] = s; red[4 + (tid >> 6)] = sq; }
  __syncthreads();
  if (tid == 0) {
    float S = red[0] + red[1] + red[2] + red[3];
    float Q = red[4] + red[5] + red[6] + red[7];
    float m = S / 1000.f;
    float var = Q / 1000.f - m * m;
    red[8] = m;
    red[9] = 1.f / sqrtf(var + 1e-3f);
  }
  __syncthreads();
  mean = red[8]; rstd = red[9];
}

// P1: xa row via one-hot gather (t>0) or xa_t0 (t=0), + LN + ELU -> xe.
__device__ void phase_p1(const ScanArgs& a, int t, float* red, int* gidx) {
  const int row = blockIdx.x, tid = threadIdx.x;
  if (t > 0 && tid < 32) gidx[tid] = cloadi(a.idx + row * 32 + tid);
  __syncthreads();
  float mk = a.mask[t * 64 + row];
  float v[4];
  float s = 0.f, sq = 0.f;
#pragma unroll
  for (int i = 0; i < 4; i++) {
    int c = tid + (i << 8);
    float x = 0.f;
    if (c < 1000) {
      if (t == 0) {
        x = a.xa_t0[row * 1024 + c];
      } else {
        float g = 0.f;
#pragma unroll
        for (int s2 = 0; s2 < 32; s2++)
          g += a.zw[(s2 * 32 + gidx[s2]) * 1000 + c];
        x = g * mk + a.xa_base[(long)t * 65536 + row * 1024 + c];
      }
      s += x; sq += x * x;
    }
    v[i] = x;
  }
  float mean, rstd;
  ln_reduce(s, sq, red, mean, rstd);
#pragma unroll
  for (int i = 0; i < 4; i++) {
    int c = tid + (i << 8);
    float y = 0.f;
    if (c < 1000) {
      y = (v[i] - mean) * rstd * a.in_g[c] + a.in_b[c];
      y = y > 0.f ? y : expm1f(y);
    }
    cstore(a.xe + row * 1024 + c, y);
  }
  __syncthreads();
}

// P5: sum 8 x2 partials + LN + ELU -> x2e.
__device__ void phase_p5(const ScanArgs& a, float* red) {
  const int row = blockIdx.x, tid = threadIdx.x;
  float v[4];
  float s = 0.f, sq = 0.f;
#pragma unroll
  for (int i = 0; i < 4; i++) {
    int c = tid + (i << 8);
    float x = 0.f;
    if (c < 1000) {
#pragma unroll
      for (int q = 0; q < 8; q++)
        x += cload(a.x2_parts + (long)q * 65536 + row * 1024 + c);
      s += x; sq += x * x;
    }
    v[i] = x;
  }
  float mean, rstd;
  ln_reduce(s, sq, red, mean, rstd);
#pragma unroll
  for (int i = 0; i < 4; i++) {
    int c = tid + (i << 8);
    float y = 0.f;
    if (c < 1000) {
      y = (v[i] - mean) * rstd * a.po_g[c] + a.po_b[c];
      y = y > 0.f ? y : expm1f(y);
    }
    cstore(a.x2e + row * 1024 + c, y);
  }
  __syncthreads();
}

// P3: GRU gates, 2 adjacent d per thread, 256 blocks.
__device__ void phase_gates(const ScanArgs& a, const float* hprev, int ldh,
                            const float* mk, float* feat_t, int t) {
  int p = blockIdx.x * 256 + threadIdx.x;  // 0..65535
  int b = p >> 10, d = (p & 1023) << 1;
  long gio = (long)b * 6144 + d;
  float r0, r1, z0, z1, n0, n1;
  {
    float2 t0 = cload2(a.gi_parts + gio);
    float2 t1 = cload2(a.gi_parts + gio + 2048);
    float2 t2 = cload2(a.gi_parts + gio + 4096);
    r0 = t0.x; r1 = t0.y; z0 = t1.x; z1 = t1.y; n0 = t2.x; n1 = t2.y;
  }
#pragma unroll
  for (int q = 1; q < 5; q++) {
    long o = (long)q * 393216 + gio;
    float2 t0 = cload2(a.gi_parts + o);
    float2 t1 = cload2(a.gi_parts + o + 2048);
    float2 t2 = cload2(a.gi_parts + o + 4096);
    r0 += t0.x; r1 += t0.y; z0 += t1.x; z1 += t1.y; n0 += t2.x; n1 += t2.y;
  }
  r0 += a.gbi[d]; r1 += a.gbi[d + 1];
  z0 += a.gbi[d + 2048]; z1 += a.gbi[d + 2049];
  n0 += a.gbi[d + 4096]; n1 += a.gbi[d + 4097];
  float hr0 = a.gbh[d], hr1 = a.gbh[d + 1];
  float hz0 = a.gbh[d + 2048], hz1 = a.gbh[d + 2049];
  float hn0 = a.gbh[d + 4096], hn1 = a.gbh[d + 4097];
#pragma unroll
  for (int q = 0; q < 8; q++) {
    long o = (long)q * 393216 + gio;
    float2 t0 = cload2(a.gh_parts + o);
    float2 t1 = cload2(a.gh_parts + o + 2048);
    float2 t2 = cload2(a.gh_parts + o + 4096);
    hr0 += t0.x; hr1 += t0.y; hz0 += t1.x; hz1 += t1.y; hn0 += t2.x; hn1 += t2.y;
  }
  float2 hp = cload2(hprev + (long)b * ldh + d);
  float m = mk[b];
  float rr0 = sigm(r0 + hr0), rr1 = sigm(r1 + hr1);
  float uu0 = sigm(z0 + hz0), uu1 = sigm(z1 + hz1);
  float nn0 = xla_tanh(n0 + rr0 * hn0), nn1 = xla_tanh(n1 + rr1 * hn1);
  float h0v = (1.f - uu0) * nn0 + uu0 * (hp.x * m);
  float h1v = (1.f - uu1) * nn1 + uu1 * (hp.y * m);
  cstore2(feat_t + (long)b * 3072 + d, h0v, h1v);
  if (t == 63) {
    a.hlast[(long)b * 2048 + d] = h0v;
    a.hlast[(long)b * 2048 + d + 1] = h1v;
  }
}

// P7: posts assembly + JAX-exact categorical sample; emits one-hot + idx.
__device__ void phase_sample(const ScanArgs& a, int t, float* feat_t) {
  int gid = blockIdx.x * 256 + threadIdx.x;  // blocks 0..255 -> gid < 65536
  int b = gid >> 10, sj = gid & 1023, j = sj & 31, sg = sj >> 5;
  float v = 0.f;
#pragma unroll
  for (int q = 0; q < 8; q++)
    v += cload(a.pp_parts + (long)q * 65536 + (long)b * 1024 + sj);
  a.posts[(long)t * 65536 + (long)b * 1024 + sj] = v;
  uint2 kt = threefry(0u, 42u, 0u, (unsigned)t);
  unsigned idx = (unsigned)(b * 1024 + sj);
  uint2 o = threefry(kt.x, kt.y, 0u, idx);
  unsigned bits = o.x ^ o.y;
  const float TINY = 1.175494350822287508e-38f;
  float u = __uint_as_float((bits >> 9) | 0x3f800000u) - 1.0f;
  u = fmaxf(TINY, u + TINY);
  float sc = v + -logf(-logf(u));
  float bs = sc;
  int bj = j;
#pragma unroll
  for (int off = 16; off >= 1; off >>= 1) {
    float os = __shfl_xor(bs, off, 32);
    int oj = __shfl_xor(bj, off, 32);
    if (os > bs || (os == bs && oj < bj)) { bs = os; bj = oj; }
  }
  float oh = (j == bj) ? 1.f : 0.f;
  a.samples[(long)t * 65536 + (long)b * 1024 + sj] = oh;
  feat_t[(long)b * 3072 + 2048 + sj] = oh;
  if (j == 0) cstorei(a.idx + b * 32 + sg, bj);
  if (t == 63) a.zlast[b * 1024 + sj] = oh;
}

__global__ __launch_bounds__(256, 2) void k_scan(ScanArgs a) {
  __shared__ float As[BK][LDP];
  __shared__ float Bs[BK][LDP];
  __shared__ float red[16];
  __shared__ int gidx[32];
  unsigned lgen = 0;
  const int bid = blockIdx.x;

  // Prologue: gh(0) = (h0*m0) @ gru_wh, chunks 0-3 then 4-7 (384 blocks each).
  for (int half = 0; half < 2; half++) {
    if (bid >= 128) {
      int i2 = bid - 128;
      int tile = i2 % 96, ks = half * 4 + i2 / 96;
      phase_gemm<TR_SCALEROW>(As, Bs, a.h0, 2048, a.gwh, 6144, ks * 256,
                              ks * 256 + 256, tile * 64, 6144, a.mask,
                              a.gh_parts + (long)ks * 393216, 6144, nullptr,
                              nullptr);
    }
    gridbar(a.bar, lgen);
  }

  for (int t = 0; t < 64; t++) {
    const float* mk = a.mask + t * 64;
    float* feat_t = a.feats + (long)t * 196608;
    const float* hprev = t ? a.feats + (long)(t - 1) * 196608 : a.h0;
    int ldh = t ? 3072 : 2048;

    // P1: xa gather + LN + ELU -> xe (64 blocks)
    if (bid < 64) phase_p1(a, t, red, gidx);
    gridbar(a.bar, lgen);

    // P2: gi = xe @ gru_wi (480 blocks: 96 tiles x 5 K-chunks of 200)
    if (bid < 480) {
      int tile = bid % 96, ks = bid / 96;
      phase_gemm<TR_NONE>(As, Bs, a.xe, 1024, a.gwi, 6144, ks * 200,
                          ks * 200 + 200, tile * 64, 6144, nullptr,
                          a.gi_parts + (long)ks * 393216, 6144, nullptr, nullptr);
    }
    gridbar(a.bar, lgen);

    // P3: gates -> h_t (256 blocks, 2 d/thread)
    if (bid < 256) phase_gates(a, hprev, ldh, mk, feat_t, t);
    gridbar(a.bar, lgen);

    // P4: x2 = h_t @ ph_w (+x2_base) (128 blk) || gh(t+1) chunks 0-3 (384 blk)
    if (bid < 128) {
      int ct = bid & 15, ks = bid >> 4;
      phase_gemm<TR_NONE>(As, Bs, feat_t, 3072, a.ph_w, 1000, ks * 256,
                          ks * 256 + 256, ct * 64, 1000, nullptr,
                          a.x2_parts + (long)ks * 65536, 1024,
                          (ks == 0) ? a.x2_base + (long)t * 65536 : nullptr,
                          nullptr);
    } else if (t < 63) {
      int i2 = bid - 128;
      int tile = i2 % 96, ks = i2 / 96;
      phase_gemm<TR_SCALEROW>(As, Bs, feat_t, 3072, a.gwh, 6144, ks * 256,
                              ks * 256 + 256, tile * 64, 6144,
                              a.mask + (t + 1) * 64,
                              a.gh_parts + (long)ks * 393216, 6144, nullptr,
                              nullptr);
    }
    gridbar(a.bar, lgen);

    // P5: x2e = elu(ln(sum x2 parts)) (64 blocks)
    if (bid < 64) phase_p5(a, red);
    gridbar(a.bar, lgen);

    // P6: pp = x2e @ pp_w (+pp_b) (128 blk) || gh(t+1) chunks 4-7 (384 blk)
    if (bid < 128) {
      int ct = bid & 15, ks = bid >> 4;
      int kB = ks * 128, kE = min(1000, kB + 128);
      phase_gemm<TR_NONE>(As, Bs, a.x2e, 1024, a.pp_w, 1024, kB, kE, ct * 64,
                          1024, nullptr, a.pp_parts + (long)ks * 65536, 1024,
                          nullptr, (ks == 0) ? a.pp_b : nullptr);
    } else if (t < 63) {
      int i2 = bid - 128;
      int tile = i2 % 96, ks = 4 + i2 / 96;
      phase_gemm<TR_SCALEROW>(As, Bs, feat_t, 3072, a.gwh, 6144, ks * 256,
                              ks * 256 + 256, tile * 64, 6144,
                              a.mask + (t + 1) * 64,
                              a.gh_parts + (long)ks * 393216, 6144, nullptr,
                              nullptr);
    }
    gridbar(a.bar, lgen);

    // P7: sample (256 blocks)
    if (bid < 256) phase_sample(a, t, feat_t);
    gridbar(a.bar, lgen);
  }
}

// ======================= small helper kernels ==============================
__global__ void k_init(unsigned* bar) {
  int i = threadIdx.x;
  if (i < 512) bar[i] = 0u;
}

__global__ void k_detect(const unsigned* rr, int nDwordsSafe, int* fmt) {
  __shared__ int flags;
  if (threadIdx.x == 0) flags = 0;
  __syncthreads();
  int local = 0;
  for (int i = threadIdx.x; i < nDwordsSafe; i += 256) {
    unsigned dw = rr[i];
    if (dw == 0x3f800000u) local |= 4;
    else if (dw & 0xFFFFFF00u) local |= 1;
    else if (dw == 1u) local |= 2;
  }
  atomicOr(&flags, local);
  __syncthreads();
  if (threadIdx.x == 0) {
    int f = flags;
    *fmt = ((f & 4) == 0 && (f & 1)) ? 1 : 0;
  }
}

__global__ void k_prep(const void* rr, const int* fmt, float* mask, int n) {
  int i = blockIdx.x * 256 + threadIdx.x;
  if (i < n) {
    bool reset;
    if (*fmt == 1) reset = ((const unsigned char*)rr)[i] != 0;
    else reset = ((const int*)rr)[i] != 0;
    mask[i] = reset ? 0.0f : 1.0f;
  }
}

__global__ __launch_bounds__(256) void k_abase(const float* act, const float* aw,
                                               const float* zb, float* out) {
  for (long i = blockIdx.x * 256L + threadIdx.x; i < 4096L * 1024;
       i += (long)gridDim.x * 256) {
    int row = (int)(i >> 10), c = (int)(i & 1023);
    float v = 0.f;
    if (c < 1000) {
      v = zb[c];
#pragma unroll
      for (int k = 0; k < 6; k++) v += act[row * 6 + k] * aw[k * 1000 + c];
    }
    out[i] = v;
  }
}

// ---------------------------------------------------------------------------
extern "C" void kernel_launch(void* const* d_in, const int* in_sizes, int n_in,
                              void* d_out, int out_size, void* d_ws, size_t ws_size,
                              hipStream_t stream) {
  const float* embeds = (const float*)d_in[0];
  const float* actions = (const float*)d_in[1];
  const void* resets = d_in[2];
  const float* h0 = (const float*)d_in[3];
  const float* z0 = (const float*)d_in[4];
  const float* zw = (const float*)d_in[5];
  const float* zb = (const float*)d_in[6];
  const float* aw = (const float*)d_in[7];
  const float* in_g = (const float*)d_in[8];
  const float* in_b = (const float*)d_in[9];
  const float* gwi = (const float*)d_in[10];
  const float* gwh = (const float*)d_in[11];
  const float* gbi = (const float*)d_in[12];
  const float* gbh = (const float*)d_in[13];
  const float* ph_w = (const float*)d_in[14];
  const float* ph_b = (const float*)d_in[15];
  const float* pe_w = (const float*)d_in[16];
  const float* po_g = (const float*)d_in[17];
  const float* po_b = (const float*)d_in[18];
  const float* pp_w = (const float*)d_in[19];
  const float* pp_b = (const float*)d_in[20];
  const float* prh_w = (const float*)d_in[21];
  const float* prh_b = (const float*)d_in[22];
  const float* pr_g = (const float*)d_in[23];
  const float* pr_b = (const float*)d_in[24];
  const float* prp_w = (const float*)d_in[25];
  const float* prp_b = (const float*)d_in[26];

  float* out = (float*)d_out;
  float* priors  = out;
  float* posts   = out + 4194304;
  float* samples = out + 8388608;
  float* feats   = out + 12582912;
  float* hlast   = out + 25165824;
  float* zlast   = out + 25296896;

  float* ws = (float*)d_ws;
  unsigned* bar   = (unsigned*)ws;            // 512 u32
  int*   fmt      = (int*)(ws + 512);
  float* mask     = ws + 576;                 // 4096
  float* stats_p  = ws + 4672;                // 8192
  float* xe       = ws + 12864;               // 65536
  float* x2e      = ws + 78400;               // 65536
  int*   idxb     = (int*)(ws + 143936);      // 2048
  float* xa_t0    = ws + 146048;              // 65536
  float* gi_parts = ws + 211584;              // 5*393216 = 1966080
  float* gh_parts = ws + 2177664;             // 8*393216 = 3145728
  float* x2_parts = ws + 5323392;             // 8*65536  = 524288
  float* pp_parts = ws + 5847680;             // 8*65536  = 524288
  float* xa_base  = ws + 6371968;             // 4194304
  float* x2_base  = ws + 10566272;            // 4194304
  float* xp       = ws + 14760576;            // 4194304 (end ~75.8 MB)

  k_init<<<1, 512, 0, stream>>>(bar);
  k_detect<<<1, 256, 0, stream>>>((const unsigned*)resets, 1024, fmt);
  k_prep<<<16, 256, 0, stream>>>(resets, fmt, mask, 4096);
  k_abase<<<2048, 256, 0, stream>>>(actions, aw, zb, xa_base);

  // xa_t0 = (z0*m0)@zw + zb + a0@aw   (dense; z0 need not be one-hot)
  GemmArgs g0{};
  g0.A = z0; g0.lda = 1024; g0.B = zw; g0.ldb = 1000; g0.K = 1024; g0.ksplit = 1;
  g0.A2 = actions; g0.lda2 = 6; g0.B2 = aw; g0.ldb2 = 1000; g0.K2 = 6;
  g0.N = 1000; g0.bias = zb; g0.t1s = mask;
  g0.C = xa_t0; g0.ldc = 1024; g0.partStride = 0;
  k_gemm<TR_SCALEROW, TR_NONE><<<dim3(16, 1, 1), 256, 0, stream>>>(g0);

  // x2_base = embeds @ pe_w + ph_b (batched 4096x1000, K=1024)
  GemmArgs ge{};
  ge.A = embeds; ge.lda = 1024; ge.B = pe_w; ge.ldb = 1000; ge.K = 1024; ge.ksplit = 1;
  ge.N = 1000; ge.bias = ph_b; ge.C = x2_base; ge.ldc = 1024; ge.partStride = 0;
  k_gemm<TR_NONE, TR_NONE><<<dim3(16, 1, 64), 256, 0, stream>>>(ge);

  // persistent 64-step scan
  ScanArgs sa{};
  sa.h0 = h0; sa.zw = zw; sa.gwi = gwi; sa.gwh = gwh;
  sa.gbi = gbi; sa.gbh = gbh; sa.ph_w = ph_w; sa.pp_w = pp_w; sa.pp_b = pp_b;
  sa.in_g = in_g; sa.in_b = in_b; sa.po_g = po_g; sa.po_b = po_b;
  sa.mask = mask; sa.xa_base = xa_base; sa.x2_base = x2_base; sa.xa_t0 = xa_t0;
  sa.gi_parts = gi_parts; sa.gh_parts = gh_parts;
  sa.x2_parts = x2_parts; sa.pp_parts = pp_parts;
  sa.xe = xe; sa.x2e = x2e; sa.idx = idxb;
  sa.posts = posts; sa.samples = samples; sa.feats = feats;
  sa.hlast = hlast; sa.zlast = zlast; sa.bar = bar;
  k_scan<<<NBLK, 256, 0, stream>>>(sa);

  // prior head (batched over all T*B rows)
  GemmArgs gp1{};
  gp1.A = feats; gp1.lda = 3072; gp1.B = prh_w; gp1.ldb = 1000; gp1.K = 2048; gp1.ksplit = 1;
  gp1.N = 1000; gp1.bias = prh_b; gp1.C = xp; gp1.ldc = 1024; gp1.partStride = 0;
  k_gemm<TR_NONE, TR_NONE><<<dim3(16, 1, 64), 256, 0, stream>>>(gp1);
  k_prstat<<<1024, 256, 0, stream>>>(xp, stats_p, 1000);
  GemmArgs gp2{};
  gp2.A = xp; gp2.lda = 1024; gp2.B = prp_w; gp2.ldb = 1024; gp2.K = 1000; gp2.ksplit = 1;
  gp2.N = 1024; gp2.bias = prp_b; gp2.t1s = stats_p; gp2.t1g = pr_g; gp2.t1b = pr_b;
  gp2.C = priors; gp2.ldc = 1024; gp2.partStride = 0;
  k_gemm<TR_LNELU, TR_NONE><<<dim3(16, 1, 64), 256, 0, stream>>>(gp2);
}